// Round 12
// baseline (979.579 us; speedup 1.0000x reference)
//
#include <hip/hip_runtime.h>
#include <hip/hip_bf16.h>
#include <hip/hip_fp16.h>

// B=8192, T=512, IN=1, H=20, OUT=1
#define B_TOTAL 8192
#define T_LEN   512
#define H       20
#define NBW     3      // batches per wave (3*20=60 lanes; 60-63 dummies -> row 3)
#define XSTR    520    // xs row stride in floats (conflict-free)
#define HROWU   12     // h row stride in uints (48B; 10 used = 20 halves)
#define WROWU   52     // packed weight row stride in uints (208B = 13 uint4)
                       // layout: word = j*52 + m*10 + q  (m=0..4, q=0..9), +2 pad

typedef _Float16 half2v __attribute__((ext_vector_type(2)));

#define FDOT2(a, b, c) __builtin_amdgcn_fdot2((a), (b), (c), false)

// tanh(x) = 1 - 2/(exp2(x*2*log2e)+1)
__device__ __forceinline__ float fast_tanh(float x) {
    float e = __builtin_amdgcn_exp2f(x * 2.885390081777927f);
    return fmaf(-2.0f, __builtin_amdgcn_rcpf(e + 1.0f), 1.0f);
}

__device__ __forceinline__ half2v h2v(unsigned int u) {
    return __builtin_bit_cast(half2v, u);
}

// Load 20 halves (10 packed pairs) from LDS: b128 + b128 + b64.
#define RDH(dst, base) \
    uint4 dst##A = ((const uint4*)(base))[0]; \
    uint4 dst##B = ((const uint4*)(base))[1]; \
    uint2 dst##C = *(const uint2*)(((const unsigned int*)(base)) + 8);

// acc0/acc1 += h . w, w given as 10 explicit packed-f16 words (load components).
#define DOTM(acc0, acc1, hv, w0,w1,w2,w3,w4,w5,w6,w7,w8,w9) \
    acc0 = FDOT2(h2v(hv##A.x), h2v(w0), acc0); acc1 = FDOT2(h2v(hv##A.y), h2v(w1), acc1); \
    acc0 = FDOT2(h2v(hv##A.z), h2v(w2), acc0); acc1 = FDOT2(h2v(hv##A.w), h2v(w3), acc1); \
    acc0 = FDOT2(h2v(hv##B.x), h2v(w4), acc0); acc1 = FDOT2(h2v(hv##B.y), h2v(w5), acc1); \
    acc0 = FDOT2(h2v(hv##B.z), h2v(w6), acc0); acc1 = FDOT2(h2v(hv##B.w), h2v(w7), acc1); \
    acc0 = FDOT2(h2v(hv##C.x), h2v(w8), acc0); acc1 = FDOT2(h2v(hv##C.y), h2v(w9), acc1);

// One diagonal-pipeline tick. Weights are re-loaded EVERY tick from the packed
// per-lane row (13 dwordx4 off one base, imm offsets 0..192). Loads are issued
// first so VMEM latency overlaps the h ds_reads. Unused loads in edge ticks DCE.
// m0=whh0: r0.x..r2.y ; m1=wih1: r2.z..r4.w ; m2=whh1: r5.x..r7.y ;
// m3=wih2: r7.z..r9.w ; m4=whh2: r10.x..r12.y
#define TICK(sidx, DO0, DO1, DO2) { \
    const uint4* wj = (const uint4*)((const unsigned char*)wpk + woff + (unsigned)(j * (WROWU * 4))); \
    uint4 r0=wj[0], r1=wj[1], r2=wj[2], r3=wj[3], r4=wj[4], r5=wj[5], r6=wj[6], \
          r7=wj[7], r8=wj[8], r9=wj[9], r10=wj[10], r11=wj[11], r12=wj[12]; \
    float t0 = 0.f, t1 = 0.f, t2 = 0.f; \
    if (DO0 || DO1) { \
        RDH(h0v, &h0s[bb][0]) \
        if (DO0) { \
            float a0 = fmaf(xs[bb][(sidx)], wih0j, bias0), a0b = 0.f; \
            DOTM(a0, a0b, h0v, r0.x,r0.y,r0.z,r0.w,r1.x,r1.y,r1.z,r1.w,r2.x,r2.y) \
            t0 = fast_tanh(a0 + a0b); \
        } \
        if (DO1) { \
            float a1 = bias1, a1b = 0.f; \
            DOTM(a1, a1b, h0v, r2.z,r2.w,r3.x,r3.y,r3.z,r3.w,r4.x,r4.y,r4.z,r4.w) \
            RDH(h1v, &h1s[bb][0]) \
            DOTM(a1, a1b, h1v, r5.x,r5.y,r5.z,r5.w,r6.x,r6.y,r6.z,r6.w,r7.x,r7.y) \
            t1 = fast_tanh(a1 + a1b); \
            if (DO2) { \
                float a2 = bias2, a2b = 0.f; \
                DOTM(a2, a2b, h1v, r7.z,r7.w,r8.x,r8.y,r8.z,r8.w,r9.x,r9.y,r9.z,r9.w) \
                RDH(h2v, &h2s[bb][0]) \
                DOTM(a2, a2b, h2v, r10.x,r10.y,r10.z,r10.w,r11.x,r11.y,r11.z,r11.w,r12.x,r12.y) \
                t2 = fast_tanh(a2 + a2b); \
            } \
        } \
    } \
    if (!(DO1) && (DO2)) { \
        RDH(h1w, &h1s[bb][0]) \
        float a2 = bias2, a2b = 0.f; \
        DOTM(a2, a2b, h1w, r7.z,r7.w,r8.x,r8.y,r8.z,r8.w,r9.x,r9.y,r9.z,r9.w) \
        RDH(h2w, &h2s[bb][0]) \
        DOTM(a2, a2b, h2w, r10.x,r10.y,r10.z,r10.w,r11.x,r11.y,r11.z,r11.w,r12.x,r12.y) \
        t2 = fast_tanh(a2 + a2b); \
    } \
    if (DO0) ((__half*)&h0s[bb][0])[j] = (__half)t0; \
    if (DO1) ((__half*)&h1s[bb][0])[j] = (__half)t1; \
    if (DO2) ((__half*)&h2s[bb][0])[j] = (__half)t2; \
}

// ---- prologue: pack 5 HxH f32 matrices into per-lane contiguous f16 rows ----
// dst word index = j*WROWU + m*10 + q
__global__ void prep_w(const float* __restrict__ w_hh0, const float* __restrict__ w_ih1,
                       const float* __restrict__ w_hh1, const float* __restrict__ w_ih2,
                       const float* __restrict__ w_hh2, unsigned int* __restrict__ ws)
{
    int i = threadIdx.x;           // 0..127; first 100 = (matrix m, row j)
    if (i < 5 * H) {
        const float* src;
        int m = i / H, j = i - m * H;
        switch (m) {
            case 0: src = w_hh0; break;
            case 1: src = w_ih1; break;
            case 2: src = w_hh1; break;
            case 3: src = w_ih2; break;
            default: src = w_hh2; break;
        }
        const float* p = src + j * H;
        unsigned int* dst = ws + j * WROWU + m * 10;
        #pragma unroll
        for (int q = 0; q < 10; ++q) {
            unsigned short lo = __builtin_bit_cast(unsigned short, (_Float16)p[2*q]);
            unsigned short hi = __builtin_bit_cast(unsigned short, (_Float16)p[2*q+1]);
            dst[q] = (unsigned int)lo | ((unsigned int)hi << 16);
        }
        if (m == 4) { dst[10] = 0u; dst[11] = 0u; }   // row pad words 50,51
    }
}

__global__ __launch_bounds__(64, 2) void rnn_wave(
    const float* __restrict__ x,
    const float* __restrict__ w_ih0,
    const float* __restrict__ b_ih0, const float* __restrict__ b_hh0,
    const float* __restrict__ b_ih1, const float* __restrict__ b_hh1,
    const float* __restrict__ b_ih2, const float* __restrict__ b_hh2,
    const float* __restrict__ fc_w,  const float* __restrict__ fc_b,
    const unsigned int* __restrict__ wpk,   // packed f16 weights, per-j rows
    float* __restrict__ out)
{
    __shared__ __align__(16) float        xs[4][XSTR];
    __shared__ __align__(16) unsigned int h0s[4][HROWU];
    __shared__ __align__(16) unsigned int h1s[4][HROWU];
    __shared__ __align__(16) unsigned int h2s[4][HROWU];

    const int lane = threadIdx.x;      // block == one wave
    const int bb   = lane / H;         // 0..3 (3 = dummy lanes)
    const int j    = lane - bb * H;    // 0..19
    const int gb   = blockIdx.x * NBW + bb;

    // ---- one-time: stage x rows (coalesced float4), zero h state ----
    {
        const int gb0 = blockIdx.x * NBW;
        #pragma unroll
        for (int it = 0; it < 6; ++it) {
            int fidx = (it * 64 + lane) * 4;
            int row  = fidx >> 9;
            int col  = fidx & 511;
            int grow = gb0 + row;
            if (grow > B_TOTAL - 1) grow = B_TOTAL - 1;
            *(float4*)&xs[row][col] = *(const float4*)(x + (size_t)grow * T_LEN + col);
        }
        for (int i = lane; i < 4 * HROWU; i += 64) {
            (&h0s[0][0])[i] = 0u;
            (&h1s[0][0])[i] = 0u;
            (&h2s[0][0])[i] = 0u;
        }
        for (int i = lane; i < XSTR; i += 64) xs[3][i] = 0.f;
    }

    const float wih0j = w_ih0[j];
    const float bias0 = b_ih0[j] + b_hh0[j];
    const float bias1 = b_ih1[j] + b_hh1[j];
    const float bias2 = b_ih2[j] + b_hh2[j];

    // Opaque byte offset (always 0) — defeats LICM so the 13 weight loads stay
    // per-tick (clean VMEM reload, L1-hot) instead of hoisted-then-spilled.
    unsigned int woff = 0;

    // ---- diagonal pipeline, wave-synchronous (no barriers) ----
    TICK(0, 1, 0, 0)
    TICK(1, 1, 1, 0)
    for (int s = 2; s < T_LEN; ++s) {
        asm volatile("" : "+v"(woff));
        TICK(s, 1, 1, 1)
    }
    TICK(512, 0, 1, 1)   // h1(511), h2(510)
    TICK(513, 0, 0, 1)   // h2(511)

    // ---- FC epilogue ----
    if (j == 0 && bb < NBW && gb < B_TOTAL) {
        float acc = fc_b[0];
        const __half* hp = (const __half*)&h2s[bb][0];
        #pragma unroll
        for (int k = 0; k < H; ++k)
            acc = fmaf((float)hp[k], fc_w[k], acc);
        out[gb] = acc;
    }
}

extern "C" void kernel_launch(void* const* d_in, const int* in_sizes, int n_in,
                              void* d_out, int out_size, void* d_ws, size_t ws_size,
                              hipStream_t stream) {
    const float* x     = (const float*)d_in[0];
    const float* w_ih0 = (const float*)d_in[1];
    const float* w_hh0 = (const float*)d_in[2];
    const float* b_ih0 = (const float*)d_in[3];
    const float* b_hh0 = (const float*)d_in[4];
    const float* w_ih1 = (const float*)d_in[5];
    const float* w_hh1 = (const float*)d_in[6];
    const float* b_ih1 = (const float*)d_in[7];
    const float* b_hh1 = (const float*)d_in[8];
    const float* w_ih2 = (const float*)d_in[9];
    const float* w_hh2 = (const float*)d_in[10];
    const float* b_ih2 = (const float*)d_in[11];
    const float* b_hh2 = (const float*)d_in[12];
    const float* fc_w  = (const float*)d_in[13];
    const float* fc_b  = (const float*)d_in[14];
    float* out = (float*)d_out;
    unsigned int* wpk = (unsigned int*)d_ws;   // needs 20*52*4 = 4160 B

    prep_w<<<1, 128, 0, stream>>>(w_hh0, w_ih1, w_hh1, w_ih2, w_hh2, wpk);

    const int nblocks = (B_TOTAL + NBW - 1) / NBW;   // 2731
    rnn_wave<<<nblocks, 64, 0, stream>>>(
        x, w_ih0, b_ih0, b_hh0, b_ih1, b_hh1, b_ih2, b_hh2,
        fc_w, fc_b, wpk, out);
}

// Round 13
// 199.619 us; speedup vs baseline: 4.9072x; 4.9072x over previous
//
#include <hip/hip_runtime.h>
#include <hip/hip_fp16.h>

// B=8192, T=512, IN=1, H=20, OUT=1
#define B_TOTAL 8192
#define T_LEN   512
#define H       20
#define XSTR    520          // xs row stride (floats): (520b+t)%32 -> 4-way max
#define WROW    16           // packed weight row stride in dwords (64B)
// wpk layout: matrix m in {0:whh0,1:wih1,2:whh1,3:wih2,4:whh2}, 32 rows each
// (rows 20..31 zero), row r: dwords 0..9 = f16 pairs of W[r][0..19], 10..15 = 0.
// A-fragment for 16x16x32: lane l (b=l&15,g=l>>4): row=b(+16), k=8g+i
//  -> dwords 4g..4g+3 of the row = one dwordx4.

typedef _Float16 f16x8 __attribute__((ext_vector_type(8)));
typedef _Float16 f16x2 __attribute__((ext_vector_type(2)));
typedef float    f32x4 __attribute__((ext_vector_type(4)));

#define MFMA(a, bf, c) __builtin_amdgcn_mfma_f32_16x16x32_f16((a), (bf), (c), 0, 0, 0)

// tanh(x) = 1 - 2/(exp2(x*2*log2e)+1)
__device__ __forceinline__ float fast_tanh(float x) {
    float e = __builtin_amdgcn_exp2f(x * 2.885390081777927f);
    return fmaf(-2.0f, __builtin_amdgcn_rcpf(e + 1.0f), 1.0f);
}

// D(f32x4, lane: col=b, rows j=4g+r) -> tanh -> f16 pairs -> h row dwords 2g,2g+1.
// Hi-tile D2 (rows j=16+r valid on g==0 lanes) -> dwords 8,9.
__device__ __forceinline__ void sth(unsigned int (*buf)[20], int b, int g,
                                    f32x4 d, f32x4 dh) {
    float t0 = fast_tanh(d[0]), t1 = fast_tanh(d[1]);
    float t2 = fast_tanh(d[2]), t3 = fast_tanh(d[3]);
    unsigned int p0 = __builtin_bit_cast(unsigned int, __builtin_amdgcn_cvt_pkrtz(t0, t1));
    unsigned int p1 = __builtin_bit_cast(unsigned int, __builtin_amdgcn_cvt_pkrtz(t2, t3));
    uint2 w; w.x = p0; w.y = p1;
    *(uint2*)&buf[b][2 * g] = w;
    if (g == 0) {
        float u0 = fast_tanh(dh[0]), u1 = fast_tanh(dh[1]);
        float u2 = fast_tanh(dh[2]), u3 = fast_tanh(dh[3]);
        uint2 v;
        v.x = __builtin_bit_cast(unsigned int, __builtin_amdgcn_cvt_pkrtz(u0, u1));
        v.y = __builtin_bit_cast(unsigned int, __builtin_amdgcn_cvt_pkrtz(u2, u3));
        *(uint2*)&buf[b][8] = v;
    }
}

// ---- prologue: pack 5 HxH f32 matrices into padded f16-pair rows ----
__global__ void prep_w(const float* __restrict__ w_hh0, const float* __restrict__ w_ih1,
                       const float* __restrict__ w_hh1, const float* __restrict__ w_ih2,
                       const float* __restrict__ w_hh2, unsigned int* __restrict__ ws)
{
    int i = threadIdx.x;                 // 256 threads, first 160 = (m, r)
    if (i < 160) {
        int m = i >> 5, r = i & 31;
        const float* src = (m == 0) ? w_hh0 : (m == 1) ? w_ih1 :
                           (m == 2) ? w_hh1 : (m == 3) ? w_ih2 : w_hh2;
        unsigned int* dst = ws + (m * 32 + r) * WROW;
        #pragma unroll
        for (int q = 0; q < 10; ++q) {
            unsigned int v = 0;
            if (r < H) {
                _Float16 lo = (_Float16)src[r * H + 2 * q];
                _Float16 hi = (_Float16)src[r * H + 2 * q + 1];
                v = (unsigned int)__builtin_bit_cast(unsigned short, lo)
                  | ((unsigned int)__builtin_bit_cast(unsigned short, hi) << 16);
            }
            dst[q] = v;
        }
        #pragma unroll
        for (int q = 10; q < 16; ++q) dst[q] = 0;
    }
}

// 3 waves/block, one RNN layer each; 16 batches/block; diagonal pipeline with
// one __syncthreads per tick. h handoff via LDS in MFMA B-fragment layout.
__global__ __launch_bounds__(192, 2) void rnn_mfma(
    const float* __restrict__ x,
    const float* __restrict__ w_ih0,
    const float* __restrict__ b_ih0, const float* __restrict__ b_hh0,
    const float* __restrict__ b_ih1, const float* __restrict__ b_hh1,
    const float* __restrict__ b_ih2, const float* __restrict__ b_hh2,
    const float* __restrict__ fc_w,  const float* __restrict__ fc_b,
    const unsigned int* __restrict__ wpk,
    float* __restrict__ out)
{
    __shared__ __align__(16) float        xs[16][XSTR];
    __shared__ __align__(16) unsigned int h0b[2][16][20];  // dbuf, wv0 -> wv1
    __shared__ __align__(16) unsigned int h1b[2][16][20];  // dbuf, wv1 -> wv2 (+self)
    __shared__ __align__(16) unsigned int h2b[16][20];     // wv2 self (in-order)

    const int tid = threadIdx.x;
    const int wv  = tid >> 6;        // wave role = layer index
    const int l   = tid & 63;
    const int b   = l & 15;          // batch within tile / A-row
    const int g   = l >> 4;          // k-chunk / D row-group
    const int gb0 = blockIdx.x * 16;

    // ---- stage x (coalesced float4) and zero h buffers ----
    for (int i = tid; i < 16 * 128; i += 192) {
        int row = i >> 7, col = (i & 127) * 4;
        *(float4*)&xs[row][col] = *(const float4*)(x + (size_t)(gb0 + row) * T_LEN + col);
    }
    for (int i = tid; i < 2 * 16 * 20; i += 192) {
        (&h0b[0][0][0])[i] = 0u;
        (&h1b[0][0][0])[i] = 0u;
    }
    for (int i = tid; i < 16 * 20; i += 192) (&h2b[0][0])[i] = 0u;

    // ---- per-wave A-fragments (4 x dwordx4 = 16 VGPRs) ----
    const int mA = (wv == 0) ? 0 : (wv == 1) ? 1 : 3;   // whh0 / wih1 / wih2
    const int mB = (wv == 0) ? 0 : (wv == 1) ? 2 : 4;   // dup  / whh1 / whh2
    const f16x8* wp = (const f16x8*)wpk;                // 4 frags per row
    const f16x8 FaLo = wp[(mA * 32 +      b) * 4 + g];
    const f16x8 FaHi = wp[(mA * 32 + 16 + b) * 4 + g];
    const f16x8 FbLo = wp[(mB * 32 +      b) * 4 + g];
    const f16x8 FbHi = wp[(mB * 32 + 16 + b) * 4 + g];

    // ---- biases in D layout: bd[r] <-> j=4g+r ; bdh[r] <-> j=16+r (g==0) ----
    const float* bi = (wv == 0) ? b_ih0 : (wv == 1) ? b_ih1 : b_ih2;
    const float* bh = (wv == 0) ? b_hh0 : (wv == 1) ? b_hh1 : b_hh2;
    f32x4 bd, bdh, w0d, w0h;
    #pragma unroll
    for (int r = 0; r < 4; ++r) {
        int j = 4 * g + r;
        bd[r]  = bi[j] + bh[j];
        bdh[r] = bi[16 + r] + bh[16 + r];
        w0d[r] = w_ih0[j];
        w0h[r] = w_ih0[16 + r];
    }

    __syncthreads();

    // ---- diagonal pipeline: tick t -> L0:h0(t), L1:h1(t-1), L2:h2(t-2) ----
    for (int t = 0; t < T_LEN + 2; ++t) {
        __syncthreads();
        const int cur = t & 1, nxt = cur ^ 1;
        if (wv == 0) {
            if (t < T_LEN) {
                f16x8 B0 = *(const f16x8*)&h0b[cur][b][4 * g];
                float xv = xs[b][t];
                f32x4 c, ch;
                #pragma unroll
                for (int r = 0; r < 4; ++r) {
                    c[r]  = fmaf(xv, w0d[r], bd[r]);
                    ch[r] = fmaf(xv, w0h[r], bdh[r]);
                }
                f32x4 d  = MFMA(FaLo, B0, c);
                f32x4 dh = MFMA(FaHi, B0, ch);
                sth(h0b[nxt], b, g, d, dh);
            }
        } else if (wv == 1) {
            if (t >= 1 && t <= T_LEN) {
                f16x8 B0 = *(const f16x8*)&h0b[cur][b][4 * g];
                f16x8 B1 = *(const f16x8*)&h1b[cur][b][4 * g];
                f32x4 d  = MFMA(FaLo, B0, bd);
                d  = MFMA(FbLo, B1, d);
                f32x4 dh = MFMA(FaHi, B0, bdh);
                dh = MFMA(FbHi, B1, dh);
                sth(h1b[nxt], b, g, d, dh);
            }
        } else {
            if (t >= 2) {
                f16x8 B1 = *(const f16x8*)&h1b[cur][b][4 * g];
                f16x8 B2 = *(const f16x8*)&h2b[b][4 * g];      // self, in-order
                f32x4 d  = MFMA(FaLo, B1, bd);
                d  = MFMA(FbLo, B2, d);
                f32x4 dh = MFMA(FaHi, B1, bdh);
                dh = MFMA(FbHi, B2, dh);
                sth(h2b, b, g, d, dh);
            }
        }
    }

    // ---- FC epilogue: wv2 owns h2(511) in h2b (same-wave, in-order) ----
    if (wv == 2 && l < 16) {
        float acc = fc_b[0];
        #pragma unroll
        for (int q = 0; q < 10; ++q) {
            f16x2 p = __builtin_bit_cast(f16x2, h2b[l][q]);
            acc = fmaf((float)p.x, fc_w[2 * q], acc);
            acc = fmaf((float)p.y, fc_w[2 * q + 1], acc);
        }
        out[gb0 + l] = acc;
    }
}

extern "C" void kernel_launch(void* const* d_in, const int* in_sizes, int n_in,
                              void* d_out, int out_size, void* d_ws, size_t ws_size,
                              hipStream_t stream) {
    const float* x     = (const float*)d_in[0];
    const float* w_ih0 = (const float*)d_in[1];
    const float* w_hh0 = (const float*)d_in[2];
    const float* b_ih0 = (const float*)d_in[3];
    const float* b_hh0 = (const float*)d_in[4];
    const float* w_ih1 = (const float*)d_in[5];
    const float* w_hh1 = (const float*)d_in[6];
    const float* b_ih1 = (const float*)d_in[7];
    const float* b_hh1 = (const float*)d_in[8];
    const float* w_ih2 = (const float*)d_in[9];
    const float* w_hh2 = (const float*)d_in[10];
    const float* b_ih2 = (const float*)d_in[11];
    const float* b_hh2 = (const float*)d_in[12];
    const float* fc_w  = (const float*)d_in[13];
    const float* fc_b  = (const float*)d_in[14];
    float* out = (float*)d_out;
    unsigned int* wpk = (unsigned int*)d_ws;   // 5 * 32 * 16 * 4 = 10240 B

    prep_w<<<1, 256, 0, stream>>>(w_hh0, w_ih1, w_hh1, w_ih2, w_hh2, wpk);

    rnn_mfma<<<B_TOTAL / 16, 192, 0, stream>>>(
        x, w_ih0, b_ih0, b_hh0, b_ih1, b_hh1, b_ih2, b_hh2,
        fc_w, fc_b, wpk, out);
}